// Round 6
// baseline (391.570 us; speedup 1.0000x reference)
//
#include <hip/hip_runtime.h>

typedef unsigned short ushort_t;
typedef __attribute__((ext_vector_type(8))) short short8;
typedef __attribute__((ext_vector_type(8))) __bf16 bf16x8;
typedef __attribute__((ext_vector_type(4))) float float4v;
typedef __attribute__((ext_vector_type(4))) unsigned int uint4v;

// ---------- bf16 helpers ----------
__device__ __forceinline__ float bf2f(ushort_t u) {
    unsigned int v = ((unsigned int)u) << 16;
    return __builtin_bit_cast(float, v);
}
__device__ __forceinline__ ushort_t f2bf(float f) {
    unsigned int u = __builtin_bit_cast(unsigned int, f);
    unsigned int lsb = (u >> 16) & 1u;
    u += 0x7fffu + lsb;  // round-to-nearest-even
    return (ushort_t)(u >> 16);
}
__device__ __forceinline__ uint4v pack8(const ushort_t* r) {
    uint4v u;
#pragma unroll
    for (int i = 0; i < 4; ++i)
        u[i] = (unsigned int)r[2 * i] | ((unsigned int)r[2 * i + 1] << 16);
    return u;
}
__device__ __forceinline__ void unpack8(uint4v u, float* f) {
#pragma unroll
    for (int i = 0; i < 4; ++i) {
        unsigned int x = u[i];
        f[2 * i] = __builtin_bit_cast(float, x << 16);
        f[2 * i + 1] = __builtin_bit_cast(float, x & 0xffff0000u);
    }
}
__device__ __forceinline__ uint4v ld8f32_bf(const float* p) {
    float4v a = *(const float4v*)p;
    float4v b = *(const float4v*)(p + 4);
    ushort_t r[8];
#pragma unroll
    for (int j = 0; j < 4; ++j) { r[j] = f2bf(a[j]); r[4 + j] = f2bf(b[j]); }
    return pack8(r);
}

// ---------- async global->LDS (16B per lane, dest = uniform base + lane*16) ----------
#if __has_builtin(__builtin_amdgcn_global_load_lds)
#define HAVE_GLDS 1
__device__ __forceinline__ void glds16(const ushort_t* gp, ushort_t* lp) {
    __builtin_amdgcn_global_load_lds((const __attribute__((address_space(1))) void*)gp,
                                     (__attribute__((address_space(3))) void*)lp, 16, 0, 0);
}
#else
#define HAVE_GLDS 0
#endif

// ---------- MFMA hedge ----------
template <typename V>
__device__ __forceinline__ auto mfma_sel(V a, V b, float4v c, int)
    -> decltype(__builtin_amdgcn_mfma_f32_16x16x32_bf16(a, b, c, 0, 0, 0)) {
    return __builtin_amdgcn_mfma_f32_16x16x32_bf16(a, b, c, 0, 0, 0);
}
template <typename V>
__device__ __forceinline__ float4v mfma_sel(V a, V b, float4v c, long) {
    return __builtin_amdgcn_mfma_f32_16x16x32_bf16(__builtin_bit_cast(bf16x8, a),
                                                   __builtin_bit_cast(bf16x8, b), c, 0, 0, 0);
}
__device__ __forceinline__ float4v mfma_bf16(short8 a, short8 b, float4v c) {
    return mfma_sel(a, b, c, 0);
}

__device__ __forceinline__ float wave_sum(float v) {
#pragma unroll
    for (int o = 32; o; o >>= 1) v += __shfl_xor(v, o);
    return v;
}

// ---------- constants ----------
#define HIDDEN 2880
#define NTOK 2048
#define QKV_DIM 5120
#define ATTN_DIM 4096
#define SM_SCALE 0.125f

// ---------- fp32 -> bf16 bulk convert ----------
__global__ __launch_bounds__(256) void f32_to_bf16_kernel(const float* __restrict__ in,
                                                          ushort_t* __restrict__ out, int n8) {
    int idx = blockIdx.x * 256 + threadIdx.x;
    if (idx < n8) *(uint4v*)(out + (size_t)idx * 8) = ld8f32_bf(in + (size_t)idx * 8);
}

// ---------- RMSNorm: fp32 x -> bf16 normed ----------
__global__ __launch_bounds__(256) void rmsnorm_kernel(const float* __restrict__ x,
                                                      const float* __restrict__ wgt,
                                                      ushort_t* __restrict__ out) {
    const int tok = blockIdx.x, tid = threadIdx.x;
    const float* xr = x + (size_t)tok * HIDDEN;
    float v[16];
    float ss = 0.f;
#pragma unroll
    for (int i = 0; i < 2; ++i) {
        int c = tid + i * 256;
        if (c < 360) {
            float4v a = *(const float4v*)(xr + c * 8);
            float4v b = *(const float4v*)(xr + c * 8 + 4);
#pragma unroll
            for (int j = 0; j < 4; ++j) { v[i * 8 + j] = a[j]; v[i * 8 + 4 + j] = b[j]; }
#pragma unroll
            for (int j = 0; j < 8; ++j) ss += v[i * 8 + j] * v[i * 8 + j];
        }
    }
    ss = wave_sum(ss);
    __shared__ float red[4];
    if ((tid & 63) == 0) red[tid >> 6] = ss;
    __syncthreads();
    float scale = rsqrtf((red[0] + red[1] + red[2] + red[3]) * (1.f / 2880.f) + 1e-5f);
#pragma unroll
    for (int i = 0; i < 2; ++i) {
        int c = tid + i * 256;
        if (c < 360) {
            float4v wa = *(const float4v*)(wgt + c * 8);
            float4v wb = *(const float4v*)(wgt + c * 8 + 4);
            ushort_t r[8];
#pragma unroll
            for (int j = 0; j < 4; ++j) {
                r[j] = f2bf(v[i * 8 + j] * scale * wa[j]);
                r[4 + j] = f2bf(v[i * 8 + 4 + j] * scale * wb[j]);
            }
            *(uint4v*)(out + (size_t)tok * HIDDEN + c * 8) = pack8(r);
        }
    }
}

// ---------- RoPE apply, YaRN cos/sin on the fly ----------
__global__ __launch_bounds__(256) void rope_apply_kernel(ushort_t* __restrict__ qkv) {
    int idx = blockIdx.x * 256 + threadIdx.x;  // 2048 * 72 * 4
    int tok = idx / 288;
    int rem = idx - tok * 288;
    int h = rem >> 2, dg = rem & 3;
    int s = tok & 1023;
    size_t base = (size_t)tok * QKV_DIM + (h < 64 ? h * 64 : 4096 + (h - 64) * 64) + dg * 8;
    uint4v u1 = *(const uint4v*)(qkv + base);
    uint4v u2 = *(const uint4v*)(qkv + base + 32);
    float f1[8], f2[8];
    unpack8(u1, f1);
    unpack8(u2, f2);
    const float step = (float)(11.918390573078392 / 32.0);
    const float conc = (float)(1.3465735902799727);
    const float low = (float)(8.092890725542669);
    const float invden = (float)(1.0 / 9.305804387286162);
    ushort_t r1[8], r2[8];
#pragma unroll
    for (int jj = 0; jj < 8; ++jj) {
        int j = dg * 8 + jj;
        float invf = __expf(-(float)j * step);
        float ramp = ((float)j - low) * invden;
        float mask = 1.f - fminf(fmaxf(ramp, 0.f), 1.f);
        float inv_freq = invf * ((1.f - mask) * 0.03125f + mask);
        float ang = (float)s * inv_freq;
        float c = cosf(ang) * conc;
        float sn = sinf(ang) * conc;
        r1[jj] = f2bf(f1[jj] * c - f2[jj] * sn);
        r2[jj] = f2bf(f2[jj] * c + f1[jj] * sn);
    }
    *(uint4v*)(qkv + base) = pack8(r1);
    *(uint4v*)(qkv + base + 32) = pack8(r2);
}

// ---------- GEMM: C[M,N] = A[M,K](bf16) @ B[N,K]^T + bias (+ resid) ----------
// BF16B path: async global_load_lds staging into unpadded 128B rows with XOR chunk
// swizzle (chunk p = c ^ (row&7)); fragment ds_read_b128 then lands 2-way bank
// aliased (free, m136). Fallback (fp32 B): padded register staging.
template <int BN, bool RESID, bool OUTF32, bool BF16B>
__global__ __launch_bounds__(256) void gemm_kernel(const ushort_t* __restrict__ A,
                                                   const void* __restrict__ B,
                                                   const float* __restrict__ bias,
                                                   const float* __restrict__ resid,
                                                   void* __restrict__ Cout, int M, int N, int K) {
    constexpr int BM = 128, BK = 64;
    constexpr int LDT = BF16B ? 64 : 72;
    static_assert(BN == 128 || BN == 96 || BN == 64, "");
    __shared__ __align__(16) ushort_t As[BM * LDT];
    __shared__ __align__(16) ushort_t Bs[BN * LDT];

    const int m0 = blockIdx.x * BM;
    const int n0 = blockIdx.y * BN;
    const int tid = threadIdx.x;
    const int w = tid >> 6, lane = tid & 63;
    const int quad = lane >> 4, l16 = lane & 15;

    constexpr int WN = BN / 2;
    constexpr int NI = WN / 16;  // 4 / 3 / 2
    const int wm = (w >> 1) * 64;
    const int wn = (w & 1) * WN;

    float4v acc[4][NI];
#pragma unroll
    for (int i = 0; i < 4; ++i)
#pragma unroll
        for (int j = 0; j < NI; ++j) acc[i][j] = (float4v){0.f, 0.f, 0.f, 0.f};

    const int nk = K / BK;

#if HAVE_GLDS
    constexpr int NAI = BM / 32;  // wave-issues for A tile
    constexpr int NBI = BN / 32;  // wave-issues for B tile
#endif
    constexpr int ACH = BM * BK / 8 / 256;
    constexpr int BCH = BN * BK / 8 / 256;

    for (int kt = 0; kt < nk; ++kt) {
        const int k0 = kt * BK;
        __syncthreads();
        if constexpr (BF16B) {
#if HAVE_GLDS
            const ushort_t* Bp = (const ushort_t*)B;
#pragma unroll
            for (int i = 0; i < NAI; ++i) {
                int sb = (w * NAI + i) * 64;
                int s = sb + lane;
                int r = s >> 3, p = s & 7, c = p ^ (r & 7);
                glds16(A + (size_t)(m0 + r) * K + k0 + c * 8, As + sb * 8);
            }
#pragma unroll
            for (int i = 0; i < NBI; ++i) {
                int sb = (w * NBI + i) * 64;
                int s = sb + lane;
                int r = s >> 3, p = s & 7, c = p ^ (r & 7);
                glds16(Bp + (size_t)(n0 + r) * K + k0 + c * 8, Bs + sb * 8);
            }
#else
#pragma unroll
            for (int i = 0; i < ACH; ++i) {
                int c = tid + i * 256, r = c >> 3, col = c & 7;
                *(uint4v*)(As + r * LDT + col * 8) =
                    *(const uint4v*)(A + (size_t)(m0 + r) * K + k0 + col * 8);
            }
#pragma unroll
            for (int i = 0; i < BCH; ++i) {
                int c = tid + i * 256, r = c >> 3, col = c & 7;
                *(uint4v*)(Bs + r * LDT + col * 8) =
                    *(const uint4v*)((const ushort_t*)B + (size_t)(n0 + r) * K + k0 + col * 8);
            }
#endif
        } else {
#pragma unroll
            for (int i = 0; i < ACH; ++i) {
                int c = tid + i * 256, r = c >> 3, col = c & 7;
                *(uint4v*)(As + r * LDT + col * 8) =
                    *(const uint4v*)(A + (size_t)(m0 + r) * K + k0 + col * 8);
            }
#pragma unroll
            for (int i = 0; i < BCH; ++i) {
                int c = tid + i * 256, r = c >> 3, col = c & 7;
                *(uint4v*)(Bs + r * LDT + col * 8) =
                    ld8f32_bf((const float*)B + (size_t)(n0 + r) * K + k0 + col * 8);
            }
        }
        __syncthreads();

#pragma unroll
        for (int ks = 0; ks < 2; ++ks) {
            short8 af[4], bfr[NI];
#pragma unroll
            for (int mi = 0; mi < 4; ++mi) {
                int row = wm + mi * 16 + l16;
                int off = BF16B ? ((ks * 4 + quad) ^ (row & 7)) * 8 : ks * 32 + quad * 8;
                af[mi] = *(const short8*)(As + row * LDT + off);
            }
#pragma unroll
            for (int ni = 0; ni < NI; ++ni) {
                int row = wn + ni * 16 + l16;
                int off = BF16B ? ((ks * 4 + quad) ^ (row & 7)) * 8 : ks * 32 + quad * 8;
                bfr[ni] = *(const short8*)(Bs + row * LDT + off);
            }
#pragma unroll
            for (int mi = 0; mi < 4; ++mi)
#pragma unroll
                for (int ni = 0; ni < NI; ++ni)
                    acc[mi][ni] = mfma_bf16(af[mi], bfr[ni], acc[mi][ni]);
        }
    }

    // epilogue: C/D layout col = lane&15, row = quad*4 + reg
#pragma unroll
    for (int ni = 0; ni < NI; ++ni) {
        int gc = n0 + wn + ni * 16 + l16;
        float bv = bias[gc];
#pragma unroll
        for (int mi = 0; mi < 4; ++mi) {
#pragma unroll
            for (int r = 0; r < 4; ++r) {
                int gr = m0 + wm + mi * 16 + quad * 4 + r;
                float vv = acc[mi][ni][r] + bv;
                if constexpr (RESID) vv += resid[(size_t)gr * N + gc];
                if constexpr (OUTF32) ((float*)Cout)[(size_t)gr * N + gc] = vv;
                else ((ushort_t*)Cout)[(size_t)gr * N + gc] = f2bf(vv);
            }
        }
    }
}

// ---------- MFMA attention: sliding window 128 + sink ----------
// Grid (qc 16, kvh*2+half 16, b 2) = 512 blocks, 2 blocks/CU (157.7KB LDS).
// Wave w handles head kvh*8 + half*4 + w, 4 query-tiles of 16.
__global__ __launch_bounds__(256, 2) void attn_mfma_kernel(const ushort_t* __restrict__ qkv,
                                                           const float* __restrict__ sinks,
                                                           ushort_t* __restrict__ attnbuf) {
    constexpr int LDK = 72, LDV = 200, LDP = 200;
    __shared__ __align__(16) ushort_t Ks[192 * LDK];
    __shared__ __align__(16) ushort_t Vt[64 * LDV];
    __shared__ __align__(16) ushort_t Pb[4][16 * LDP];

    const int qc = blockIdx.x, kvh = blockIdx.y >> 1, half = blockIdx.y & 1, b = blockIdx.z;
    const int tid = threadIdx.x;
    const int w = tid >> 6, lane = tid & 63;
    const int quad = lane >> 4, l16 = lane & 15;
    const int w0 = qc * 64 - 127;  // key position of LDS row 0

    for (int c = tid; c < 192 * 8; c += 256) {
        int row = c >> 3, col8 = c & 7;
        int pos = w0 + row;
        pos = pos < 0 ? 0 : (pos > 1023 ? 1023 : pos);
        size_t gk = ((size_t)(b * 1024 + pos)) * QKV_DIM + 4096 + kvh * 64 + col8 * 8;
        *(uint4v*)(Ks + row * LDK + col8 * 8) = *(const uint4v*)(qkv + gk);
        uint4v vv = *(const uint4v*)(qkv + gk + 512);
        ushort_t vs[8];
#pragma unroll
        for (int i = 0; i < 4; ++i) {
            vs[2 * i] = (ushort_t)(vv[i] & 0xffffu);
            vs[2 * i + 1] = (ushort_t)(vv[i] >> 16);
        }
#pragma unroll
        for (int j = 0; j < 8; ++j) Vt[(col8 * 8 + j) * LDV + row] = vs[j];
    }
    __syncthreads();

    // hoist V B-fragments: k = kt*32+quad*8+j, dim = nv*16+l16
    short8 Vf[6][4];
#pragma unroll
    for (int kt = 0; kt < 6; ++kt)
#pragma unroll
        for (int nv = 0; nv < 4; ++nv)
            Vf[kt][nv] = *(const short8*)(Vt + (nv * 16 + l16) * LDV + kt * 32 + quad * 8);

    ushort_t* Pw = Pb[w];
    const int h = kvh * 8 + half * 4 + w;
    const float sink_f = sinks[h];

    for (int qtile = 0; qtile < 4; ++qtile) {
        const int tokb = b * 1024 + qc * 64 + qtile * 16;

        short8 qf[2];
        {
            const ushort_t* qp = qkv + ((size_t)(tokb + l16)) * QKV_DIM + h * 64 + quad * 8;
            qf[0] = *(const short8*)qp;
            qf[1] = *(const short8*)(qp + 32);
        }

        float4v acc[12];
#pragma unroll
        for (int nt = 0; nt < 12; ++nt) acc[nt] = (float4v){0.f, 0.f, 0.f, 0.f};
#pragma unroll
        for (int nt = 0; nt < 12; ++nt) {
#pragma unroll
            for (int ks = 0; ks < 2; ++ks) {
                short8 kf = *(const short8*)(Ks + (nt * 16 + l16) * LDK + ks * 32 + quad * 8);
                acc[nt] = mfma_bf16(qf[ks], kf, acc[nt]);
            }
        }

        float linv[4];
#pragma unroll
        for (int r = 0; r < 4; ++r) {
            const int ql = qtile * 16 + quad * 4 + r;
            float e[12];
            float mx = -1e30f;
#pragma unroll
            for (int nt = 0; nt < 12; ++nt) {
                int row_k = nt * 16 + l16;
                bool valid = (row_k >= ql) && (row_k <= ql + 127) && (w0 + row_k >= 0);
                float s = valid ? acc[nt][r] * SM_SCALE : -1e30f;
                e[nt] = s;
                mx = fmaxf(mx, s);
            }
#pragma unroll
            for (int o = 1; o < 16; o <<= 1) mx = fmaxf(mx, __shfl_xor(mx, o));
            float M = fmaxf(mx, sink_f);
            float ls = 0.f;
#pragma unroll
            for (int nt = 0; nt < 12; ++nt) {
                float ev = (e[nt] > -1e29f) ? __expf(e[nt] - M) : 0.f;
                e[nt] = ev;
                ls += ev;
            }
#pragma unroll
            for (int o = 1; o < 16; o <<= 1) ls += __shfl_xor(ls, o);
            linv[r] = 1.f / (ls + __expf(sink_f - M));
#pragma unroll
            for (int nt = 0; nt < 12; ++nt)
                Pw[(quad * 4 + r) * LDP + nt * 16 + l16] = f2bf(e[nt]);
        }

        float4v accO[4];
#pragma unroll
        for (int nv = 0; nv < 4; ++nv) accO[nv] = (float4v){0.f, 0.f, 0.f, 0.f};
#pragma unroll
        for (int kt = 0; kt < 6; ++kt) {
            short8 pf = *(const short8*)(Pw + l16 * LDP + kt * 32 + quad * 8);
#pragma unroll
            for (int nv = 0; nv < 4; ++nv) accO[nv] = mfma_bf16(pf, Vf[kt][nv], accO[nv]);
        }

#pragma unroll
        for (int r = 0; r < 4; ++r) {
            size_t ob = ((size_t)(tokb + quad * 4 + r)) * ATTN_DIM + h * 64 + l16;
#pragma unroll
            for (int nv = 0; nv < 4; ++nv)
                attnbuf[ob + nv * 16] = f2bf(accO[nv][r] * linv[r]);
        }
    }
}

// ---------- launch ----------
extern "C" void kernel_launch(void* const* d_in, const int* in_sizes, int n_in,
                              void* d_out, int out_size, void* d_ws, size_t ws_size,
                              hipStream_t stream) {
    const float* x = (const float*)d_in[0];
    const float* norm_w = (const float*)d_in[1];
    const float* qkv_w = (const float*)d_in[2];
    const float* qkv_b = (const float*)d_in[3];
    const float* out_w = (const float*)d_in[4];
    const float* out_b = (const float*)d_in[5];
    const float* sinks = (const float*)d_in[6];
    float* outp = (float*)d_out;
    char* ws = (char*)d_ws;

    if (ws_size >= 86000000ull) {
        // qkvbuf 21MB | {qkv_w_bf 29.5MB -> attnbuf 16.8MB} | Tbuf 11.8MB | out_w_bf 23.6MB
        ushort_t* qkvbuf = (ushort_t*)ws;
        ushort_t* qkv_w_bf = (ushort_t*)(ws + 20971520);
        ushort_t* attnbuf = (ushort_t*)(ws + 20971520);  // reuse after gemm1 consumed qkv_w_bf
        ushort_t* Tbuf = (ushort_t*)(ws + 50462720);
        ushort_t* out_w_bf = (ushort_t*)(ws + 62259200);

        f32_to_bf16_kernel<<<7200, 256, 0, stream>>>(qkv_w, qkv_w_bf, 1843200);
        f32_to_bf16_kernel<<<5760, 256, 0, stream>>>(out_w, out_w_bf, 1474560);
        rmsnorm_kernel<<<NTOK, 256, 0, stream>>>(x, norm_w, Tbuf);
        gemm_kernel<128, false, false, true><<<dim3(16, 40), 256, 0, stream>>>(
            Tbuf, qkv_w_bf, qkv_b, nullptr, qkvbuf, NTOK, QKV_DIM, HIDDEN);
        rope_apply_kernel<<<2304, 256, 0, stream>>>(qkvbuf);
        attn_mfma_kernel<<<dim3(16, 16, 2), 256, 0, stream>>>(qkvbuf, sinks, attnbuf);
        gemm_kernel<96, true, true, true><<<dim3(16, 30), 256, 0, stream>>>(
            attnbuf, out_w_bf, out_b, x, outp, NTOK, HIDDEN, ATTN_DIM);
    } else {
        // fallback: fp32 B loads (register staging), Tbuf in d_out
        ushort_t* qkvbuf = (ushort_t*)ws;
        ushort_t* attnbuf = (ushort_t*)(ws + 20971520);
        ushort_t* Tbuf = (ushort_t*)d_out;

        rmsnorm_kernel<<<NTOK, 256, 0, stream>>>(x, norm_w, Tbuf);
        gemm_kernel<128, false, false, false><<<dim3(16, 40), 256, 0, stream>>>(
            Tbuf, qkv_w, qkv_b, nullptr, qkvbuf, NTOK, QKV_DIM, HIDDEN);
        rope_apply_kernel<<<2304, 256, 0, stream>>>(qkvbuf);
        attn_mfma_kernel<<<dim3(16, 16, 2), 256, 0, stream>>>(qkvbuf, sinks, attnbuf);
        gemm_kernel<96, true, true, false><<<dim3(16, 30), 256, 0, stream>>>(
            attnbuf, out_w, out_b, x, outp, NTOK, HIDDEN, ATTN_DIM);
    }
}

// Round 7
// 344.226 us; speedup vs baseline: 1.1375x; 1.1375x over previous
//
#include <hip/hip_runtime.h>

typedef unsigned short ushort_t;
typedef __attribute__((ext_vector_type(8))) short short8;
typedef __attribute__((ext_vector_type(8))) __bf16 bf16x8;
typedef __attribute__((ext_vector_type(4))) float float4v;
typedef __attribute__((ext_vector_type(4))) unsigned int uint4v;

// ---------- bf16 helpers ----------
__device__ __forceinline__ float bf2f(ushort_t u) {
    unsigned int v = ((unsigned int)u) << 16;
    return __builtin_bit_cast(float, v);
}
__device__ __forceinline__ ushort_t f2bf(float f) {
    unsigned int u = __builtin_bit_cast(unsigned int, f);
    unsigned int lsb = (u >> 16) & 1u;
    u += 0x7fffu + lsb;  // round-to-nearest-even
    return (ushort_t)(u >> 16);
}
__device__ __forceinline__ uint4v pack8(const ushort_t* r) {
    uint4v u;
#pragma unroll
    for (int i = 0; i < 4; ++i)
        u[i] = (unsigned int)r[2 * i] | ((unsigned int)r[2 * i + 1] << 16);
    return u;
}
__device__ __forceinline__ void unpack8(uint4v u, float* f) {
#pragma unroll
    for (int i = 0; i < 4; ++i) {
        unsigned int x = u[i];
        f[2 * i] = __builtin_bit_cast(float, x << 16);
        f[2 * i + 1] = __builtin_bit_cast(float, x & 0xffff0000u);
    }
}
__device__ __forceinline__ uint4v ld8f32_bf(const float* p) {
    float4v a = *(const float4v*)p;
    float4v b = *(const float4v*)(p + 4);
    ushort_t r[8];
#pragma unroll
    for (int j = 0; j < 4; ++j) { r[j] = f2bf(a[j]); r[4 + j] = f2bf(b[j]); }
    return pack8(r);
}

// ---------- async global->LDS (16B per lane, dest = uniform base + lane*16) ----------
#if __has_builtin(__builtin_amdgcn_global_load_lds)
#define HAVE_GLDS 1
__device__ __forceinline__ void glds16(const ushort_t* gp, ushort_t* lp) {
    __builtin_amdgcn_global_load_lds((const __attribute__((address_space(1))) void*)gp,
                                     (__attribute__((address_space(3))) void*)lp, 16, 0, 0);
}
#else
#define HAVE_GLDS 0
#endif

// ---------- MFMA hedge ----------
template <typename V>
__device__ __forceinline__ auto mfma_sel(V a, V b, float4v c, int)
    -> decltype(__builtin_amdgcn_mfma_f32_16x16x32_bf16(a, b, c, 0, 0, 0)) {
    return __builtin_amdgcn_mfma_f32_16x16x32_bf16(a, b, c, 0, 0, 0);
}
template <typename V>
__device__ __forceinline__ float4v mfma_sel(V a, V b, float4v c, long) {
    return __builtin_amdgcn_mfma_f32_16x16x32_bf16(__builtin_bit_cast(bf16x8, a),
                                                   __builtin_bit_cast(bf16x8, b), c, 0, 0, 0);
}
__device__ __forceinline__ float4v mfma_bf16(short8 a, short8 b, float4v c) {
    return mfma_sel(a, b, c, 0);
}

__device__ __forceinline__ float wave_sum(float v) {
#pragma unroll
    for (int o = 32; o; o >>= 1) v += __shfl_xor(v, o);
    return v;
}

// ---------- constants ----------
#define HIDDEN 2880
#define NTOK 2048
#define QKV_DIM 5120
#define ATTN_DIM 4096
#define SM_SCALE 0.125f

// ---------- fp32 -> bf16 bulk convert ----------
__global__ __launch_bounds__(256) void f32_to_bf16_kernel(const float* __restrict__ in,
                                                          ushort_t* __restrict__ out, int n8) {
    int idx = blockIdx.x * 256 + threadIdx.x;
    if (idx < n8) *(uint4v*)(out + (size_t)idx * 8) = ld8f32_bf(in + (size_t)idx * 8);
}

// ---------- RMSNorm: fp32 x -> bf16 normed ----------
__global__ __launch_bounds__(256) void rmsnorm_kernel(const float* __restrict__ x,
                                                      const float* __restrict__ wgt,
                                                      ushort_t* __restrict__ out) {
    const int tok = blockIdx.x, tid = threadIdx.x;
    const float* xr = x + (size_t)tok * HIDDEN;
    float v[16];
    float ss = 0.f;
#pragma unroll
    for (int i = 0; i < 2; ++i) {
        int c = tid + i * 256;
        if (c < 360) {
            float4v a = *(const float4v*)(xr + c * 8);
            float4v b = *(const float4v*)(xr + c * 8 + 4);
#pragma unroll
            for (int j = 0; j < 4; ++j) { v[i * 8 + j] = a[j]; v[i * 8 + 4 + j] = b[j]; }
#pragma unroll
            for (int j = 0; j < 8; ++j) ss += v[i * 8 + j] * v[i * 8 + j];
        }
    }
    ss = wave_sum(ss);
    __shared__ float red[4];
    if ((tid & 63) == 0) red[tid >> 6] = ss;
    __syncthreads();
    float scale = rsqrtf((red[0] + red[1] + red[2] + red[3]) * (1.f / 2880.f) + 1e-5f);
#pragma unroll
    for (int i = 0; i < 2; ++i) {
        int c = tid + i * 256;
        if (c < 360) {
            float4v wa = *(const float4v*)(wgt + c * 8);
            float4v wb = *(const float4v*)(wgt + c * 8 + 4);
            ushort_t r[8];
#pragma unroll
            for (int j = 0; j < 4; ++j) {
                r[j] = f2bf(v[i * 8 + j] * scale * wa[j]);
                r[4 + j] = f2bf(v[i * 8 + 4 + j] * scale * wb[j]);
            }
            *(uint4v*)(out + (size_t)tok * HIDDEN + c * 8) = pack8(r);
        }
    }
}

// ---------- RoPE apply, YaRN cos/sin on the fly ----------
__global__ __launch_bounds__(256) void rope_apply_kernel(ushort_t* __restrict__ qkv) {
    int idx = blockIdx.x * 256 + threadIdx.x;  // 2048 * 72 * 4
    int tok = idx / 288;
    int rem = idx - tok * 288;
    int h = rem >> 2, dg = rem & 3;
    int s = tok & 1023;
    size_t base = (size_t)tok * QKV_DIM + (h < 64 ? h * 64 : 4096 + (h - 64) * 64) + dg * 8;
    uint4v u1 = *(const uint4v*)(qkv + base);
    uint4v u2 = *(const uint4v*)(qkv + base + 32);
    float f1[8], f2[8];
    unpack8(u1, f1);
    unpack8(u2, f2);
    const float step = (float)(11.918390573078392 / 32.0);
    const float conc = (float)(1.3465735902799727);
    const float low = (float)(8.092890725542669);
    const float invden = (float)(1.0 / 9.305804387286162);
    ushort_t r1[8], r2[8];
#pragma unroll
    for (int jj = 0; jj < 8; ++jj) {
        int j = dg * 8 + jj;
        float invf = __expf(-(float)j * step);
        float ramp = ((float)j - low) * invden;
        float mask = 1.f - fminf(fmaxf(ramp, 0.f), 1.f);
        float inv_freq = invf * ((1.f - mask) * 0.03125f + mask);
        float ang = (float)s * inv_freq;
        float c = cosf(ang) * conc;
        float sn = sinf(ang) * conc;
        r1[jj] = f2bf(f1[jj] * c - f2[jj] * sn);
        r2[jj] = f2bf(f2[jj] * c + f1[jj] * sn);
    }
    *(uint4v*)(qkv + base) = pack8(r1);
    *(uint4v*)(qkv + base + 32) = pack8(r2);
}

// ---------- GEMM: C[M,N] = A[M,K](bf16) @ B[N,K]^T + bias (+ resid) ----------
// Grid: blockIdx.x = N tile (fast axis -> consecutive blocks share the A tile, L2-friendly),
//       blockIdx.y = M tile.
// GL path (BF16B + global_load_lds): double-buffered LDS, one barrier per K-iter:
//   issue async tile k+1 -> buf^1, compute tile k from buf, barrier (vmcnt drain lands
//   after the compute phase). XOR chunk swizzle (p = c ^ (row&7)) -> 0 bank conflicts.
// Fallback: padded LDS + register prefetch (round-5 structure).
template <int BN, bool RESID, bool OUTF32, bool BF16B>
__global__ __launch_bounds__(256) void gemm_kernel(const ushort_t* __restrict__ A,
                                                   const void* __restrict__ B,
                                                   const float* __restrict__ bias,
                                                   const float* __restrict__ resid,
                                                   void* __restrict__ Cout, int M, int N, int K) {
    constexpr int BM = 128, BK = 64;
    constexpr bool GL = BF16B && (HAVE_GLDS != 0);
    constexpr int LDT = GL ? 64 : 72;
    constexpr int NBUF = GL ? 2 : 1;
    static_assert(BN == 128 || BN == 96 || BN == 64, "");
    __shared__ __align__(16) ushort_t As[NBUF][BM * LDT];
    __shared__ __align__(16) ushort_t Bs[NBUF][BN * LDT];

    const int m0 = blockIdx.y * BM;
    const int n0 = blockIdx.x * BN;
    const int tid = threadIdx.x;
    const int w = tid >> 6, lane = tid & 63;
    const int quad = lane >> 4, l16 = lane & 15;

    constexpr int WN = BN / 2;
    constexpr int NI = WN / 16;  // 4 / 3 / 2
    const int wm = (w >> 1) * 64;
    const int wn = (w & 1) * WN;

    float4v acc[4][NI];
#pragma unroll
    for (int i = 0; i < 4; ++i)
#pragma unroll
        for (int j = 0; j < NI; ++j) acc[i][j] = (float4v){0.f, 0.f, 0.f, 0.f};

    const int nk = K / BK;

#if HAVE_GLDS
    if constexpr (GL) {
        constexpr int NAI = BM / 32;  // glds issues per wave for A
        constexpr int NBI = BN / 32;  // glds issues per wave for B
        const ushort_t* Bp = (const ushort_t*)B;
        const ushort_t* agp[NAI];
        const ushort_t* bgp[NBI];
        ushort_t* alp[2][NAI];
        ushort_t* blp[2][NBI];
#pragma unroll
        for (int i = 0; i < NAI; ++i) {
            int sb = (w * NAI + i) * 64;
            int s = sb + lane, r = s >> 3, p = s & 7, c = p ^ (r & 7);
            agp[i] = A + (size_t)(m0 + r) * K + c * 8;
            alp[0][i] = &As[0][sb * 8];
            alp[1][i] = &As[1][sb * 8];
        }
#pragma unroll
        for (int i = 0; i < NBI; ++i) {
            int sb = (w * NBI + i) * 64;
            int s = sb + lane, r = s >> 3, p = s & 7, c = p ^ (r & 7);
            bgp[i] = Bp + (size_t)(n0 + r) * K + c * 8;
            blp[0][i] = &Bs[0][sb * 8];
            blp[1][i] = &Bs[1][sb * 8];
        }
        // prologue: tile 0 -> buf 0
#pragma unroll
        for (int i = 0; i < NAI; ++i) glds16(agp[i], alp[0][i]);
#pragma unroll
        for (int i = 0; i < NBI; ++i) glds16(bgp[i], blp[0][i]);
        __syncthreads();

        for (int kt = 0; kt < nk; ++kt) {
            const int cur = kt & 1;
            if (kt + 1 < nk) {
                const int k0 = (kt + 1) * BK;
#pragma unroll
                for (int i = 0; i < NAI; ++i) glds16(agp[i] + k0, alp[cur ^ 1][i]);
#pragma unroll
                for (int i = 0; i < NBI; ++i) glds16(bgp[i] + k0, blp[cur ^ 1][i]);
            }
            const ushort_t* Asb = As[cur];
            const ushort_t* Bsb = Bs[cur];
#pragma unroll
            for (int ks = 0; ks < 2; ++ks) {
                short8 af[4], bfr[NI];
#pragma unroll
                for (int mi = 0; mi < 4; ++mi) {
                    int row = wm + mi * 16 + l16;
                    af[mi] = *(const short8*)(Asb + row * LDT + ((ks * 4 + quad) ^ (row & 7)) * 8);
                }
#pragma unroll
                for (int ni = 0; ni < NI; ++ni) {
                    int row = wn + ni * 16 + l16;
                    bfr[ni] = *(const short8*)(Bsb + row * LDT + ((ks * 4 + quad) ^ (row & 7)) * 8);
                }
#pragma unroll
                for (int mi = 0; mi < 4; ++mi)
#pragma unroll
                    for (int ni = 0; ni < NI; ++ni)
                        acc[mi][ni] = mfma_bf16(af[mi], bfr[ni], acc[mi][ni]);
            }
            __syncthreads();
        }
    } else
#endif
    {
        // fallback: padded LDS + register prefetch (round-5 structure)
        constexpr int ACH = BM * BK / 8 / 256;
        constexpr int BCH = BN * BK / 8 / 256;
        uint4v areg[ACH], breg[BCH];
#pragma unroll
        for (int i = 0; i < ACH; ++i) {
            int c = tid + i * 256, r = c >> 3, col = c & 7;
            areg[i] = *(const uint4v*)(A + (size_t)(m0 + r) * K + col * 8);
        }
#pragma unroll
        for (int i = 0; i < BCH; ++i) {
            int c = tid + i * 256, r = c >> 3, col = c & 7;
            if constexpr (BF16B)
                breg[i] = *(const uint4v*)((const ushort_t*)B + (size_t)(n0 + r) * K + col * 8);
            else
                breg[i] = ld8f32_bf((const float*)B + (size_t)(n0 + r) * K + col * 8);
        }
        for (int kt = 0; kt < nk; ++kt) {
            __syncthreads();
#pragma unroll
            for (int i = 0; i < ACH; ++i) {
                int c = tid + i * 256, r = c >> 3, col = c & 7;
                *(uint4v*)(&As[0][r * LDT + col * 8]) = areg[i];
            }
#pragma unroll
            for (int i = 0; i < BCH; ++i) {
                int c = tid + i * 256, r = c >> 3, col = c & 7;
                *(uint4v*)(&Bs[0][r * LDT + col * 8]) = breg[i];
            }
            __syncthreads();
            if (kt + 1 < nk) {
                const int k0 = (kt + 1) * BK;
#pragma unroll
                for (int i = 0; i < ACH; ++i) {
                    int c = tid + i * 256, r = c >> 3, col = c & 7;
                    areg[i] = *(const uint4v*)(A + (size_t)(m0 + r) * K + k0 + col * 8);
                }
#pragma unroll
                for (int i = 0; i < BCH; ++i) {
                    int c = tid + i * 256, r = c >> 3, col = c & 7;
                    if constexpr (BF16B)
                        breg[i] = *(const uint4v*)((const ushort_t*)B + (size_t)(n0 + r) * K + k0 + col * 8);
                    else
                        breg[i] = ld8f32_bf((const float*)B + (size_t)(n0 + r) * K + k0 + col * 8);
                }
            }
#pragma unroll
            for (int ks = 0; ks < 2; ++ks) {
                short8 af[4], bfr[NI];
#pragma unroll
                for (int mi = 0; mi < 4; ++mi)
                    af[mi] = *(const short8*)(&As[0][(wm + mi * 16 + l16) * LDT + ks * 32 + quad * 8]);
#pragma unroll
                for (int ni = 0; ni < NI; ++ni)
                    bfr[ni] = *(const short8*)(&Bs[0][(wn + ni * 16 + l16) * LDT + ks * 32 + quad * 8]);
#pragma unroll
                for (int mi = 0; mi < 4; ++mi)
#pragma unroll
                    for (int ni = 0; ni < NI; ++ni)
                        acc[mi][ni] = mfma_bf16(af[mi], bfr[ni], acc[mi][ni]);
            }
        }
    }

    // epilogue: C/D layout col = lane&15, row = quad*4 + reg
#pragma unroll
    for (int ni = 0; ni < NI; ++ni) {
        int gc = n0 + wn + ni * 16 + l16;
        float bv = bias[gc];
#pragma unroll
        for (int mi = 0; mi < 4; ++mi) {
#pragma unroll
            for (int r = 0; r < 4; ++r) {
                int gr = m0 + wm + mi * 16 + quad * 4 + r;
                float vv = acc[mi][ni][r] + bv;
                if constexpr (RESID) vv += resid[(size_t)gr * N + gc];
                if constexpr (OUTF32) ((float*)Cout)[(size_t)gr * N + gc] = vv;
                else ((ushort_t*)Cout)[(size_t)gr * N + gc] = f2bf(vv);
            }
        }
    }
}

// ---------- MFMA attention: sliding window 128 + sink ----------
// Grid (qc 16, kvh*2+half 16, b 2) = 512 blocks, 2 blocks/CU (157.7KB LDS).
// Wave w handles head kvh*8 + half*4 + w, 4 query-tiles of 16.
__global__ __launch_bounds__(256, 2) void attn_mfma_kernel(const ushort_t* __restrict__ qkv,
                                                           const float* __restrict__ sinks,
                                                           ushort_t* __restrict__ attnbuf) {
    constexpr int LDK = 72, LDV = 200, LDP = 200;
    __shared__ __align__(16) ushort_t Ks[192 * LDK];
    __shared__ __align__(16) ushort_t Vt[64 * LDV];
    __shared__ __align__(16) ushort_t Pb[4][16 * LDP];

    const int qc = blockIdx.x, kvh = blockIdx.y >> 1, half = blockIdx.y & 1, b = blockIdx.z;
    const int tid = threadIdx.x;
    const int w = tid >> 6, lane = tid & 63;
    const int quad = lane >> 4, l16 = lane & 15;
    const int w0 = qc * 64 - 127;  // key position of LDS row 0

    for (int c = tid; c < 192 * 8; c += 256) {
        int row = c >> 3, col8 = c & 7;
        int pos = w0 + row;
        pos = pos < 0 ? 0 : (pos > 1023 ? 1023 : pos);
        size_t gk = ((size_t)(b * 1024 + pos)) * QKV_DIM + 4096 + kvh * 64 + col8 * 8;
        *(uint4v*)(Ks + row * LDK + col8 * 8) = *(const uint4v*)(qkv + gk);
        uint4v vv = *(const uint4v*)(qkv + gk + 512);
        ushort_t vs[8];
#pragma unroll
        for (int i = 0; i < 4; ++i) {
            vs[2 * i] = (ushort_t)(vv[i] & 0xffffu);
            vs[2 * i + 1] = (ushort_t)(vv[i] >> 16);
        }
#pragma unroll
        for (int j = 0; j < 8; ++j) Vt[(col8 * 8 + j) * LDV + row] = vs[j];
    }
    __syncthreads();

    // hoist V B-fragments: k = kt*32+quad*8+j, dim = nv*16+l16
    short8 Vf[6][4];
#pragma unroll
    for (int kt = 0; kt < 6; ++kt)
#pragma unroll
        for (int nv = 0; nv < 4; ++nv)
            Vf[kt][nv] = *(const short8*)(Vt + (nv * 16 + l16) * LDV + kt * 32 + quad * 8);

    ushort_t* Pw = Pb[w];
    const int h = kvh * 8 + half * 4 + w;
    const float sink_f = sinks[h];

    for (int qtile = 0; qtile < 4; ++qtile) {
        const int tokb = b * 1024 + qc * 64 + qtile * 16;

        short8 qf[2];
        {
            const ushort_t* qp = qkv + ((size_t)(tokb + l16)) * QKV_DIM + h * 64 + quad * 8;
            qf[0] = *(const short8*)qp;
            qf[1] = *(const short8*)(qp + 32);
        }

        float4v acc[12];
#pragma unroll
        for (int nt = 0; nt < 12; ++nt) acc[nt] = (float4v){0.f, 0.f, 0.f, 0.f};
#pragma unroll
        for (int nt = 0; nt < 12; ++nt) {
#pragma unroll
            for (int ks = 0; ks < 2; ++ks) {
                short8 kf = *(const short8*)(Ks + (nt * 16 + l16) * LDK + ks * 32 + quad * 8);
                acc[nt] = mfma_bf16(qf[ks], kf, acc[nt]);
            }
        }

        float linv[4];
#pragma unroll
        for (int r = 0; r < 4; ++r) {
            const int ql = qtile * 16 + quad * 4 + r;
            float e[12];
            float mx = -1e30f;
#pragma unroll
            for (int nt = 0; nt < 12; ++nt) {
                int row_k = nt * 16 + l16;
                bool valid = (row_k >= ql) && (row_k <= ql + 127) && (w0 + row_k >= 0);
                float s = valid ? acc[nt][r] * SM_SCALE : -1e30f;
                e[nt] = s;
                mx = fmaxf(mx, s);
            }
#pragma unroll
            for (int o = 1; o < 16; o <<= 1) mx = fmaxf(mx, __shfl_xor(mx, o));
            float M = fmaxf(mx, sink_f);
            float ls = 0.f;
#pragma unroll
            for (int nt = 0; nt < 12; ++nt) {
                float ev = (e[nt] > -1e29f) ? __expf(e[nt] - M) : 0.f;
                e[nt] = ev;
                ls += ev;
            }
#pragma unroll
            for (int o = 1; o < 16; o <<= 1) ls += __shfl_xor(ls, o);
            linv[r] = 1.f / (ls + __expf(sink_f - M));
#pragma unroll
            for (int nt = 0; nt < 12; ++nt)
                Pw[(quad * 4 + r) * LDP + nt * 16 + l16] = f2bf(e[nt]);
        }

        float4v accO[4];
#pragma unroll
        for (int nv = 0; nv < 4; ++nv) accO[nv] = (float4v){0.f, 0.f, 0.f, 0.f};
#pragma unroll
        for (int kt = 0; kt < 6; ++kt) {
            short8 pf = *(const short8*)(Pw + l16 * LDP + kt * 32 + quad * 8);
#pragma unroll
            for (int nv = 0; nv < 4; ++nv) accO[nv] = mfma_bf16(pf, Vf[kt][nv], accO[nv]);
        }

#pragma unroll
        for (int r = 0; r < 4; ++r) {
            size_t ob = ((size_t)(tokb + quad * 4 + r)) * ATTN_DIM + h * 64 + l16;
#pragma unroll
            for (int nv = 0; nv < 4; ++nv)
                attnbuf[ob + nv * 16] = f2bf(accO[nv][r] * linv[r]);
        }
    }
}

// ---------- launch ----------
extern "C" void kernel_launch(void* const* d_in, const int* in_sizes, int n_in,
                              void* d_out, int out_size, void* d_ws, size_t ws_size,
                              hipStream_t stream) {
    const float* x = (const float*)d_in[0];
    const float* norm_w = (const float*)d_in[1];
    const float* qkv_w = (const float*)d_in[2];
    const float* qkv_b = (const float*)d_in[3];
    const float* out_w = (const float*)d_in[4];
    const float* out_b = (const float*)d_in[5];
    const float* sinks = (const float*)d_in[6];
    float* outp = (float*)d_out;
    char* ws = (char*)d_ws;

    if (ws_size >= 86000000ull) {
        // qkvbuf 21MB | {qkv_w_bf 29.5MB -> attnbuf 16.8MB} | Tbuf 11.8MB | out_w_bf 23.6MB
        ushort_t* qkvbuf = (ushort_t*)ws;
        ushort_t* qkv_w_bf = (ushort_t*)(ws + 20971520);
        ushort_t* attnbuf = (ushort_t*)(ws + 20971520);  // reuse after gemm1 consumed qkv_w_bf
        ushort_t* Tbuf = (ushort_t*)(ws + 50462720);
        ushort_t* out_w_bf = (ushort_t*)(ws + 62259200);

        f32_to_bf16_kernel<<<7200, 256, 0, stream>>>(qkv_w, qkv_w_bf, 1843200);
        f32_to_bf16_kernel<<<5760, 256, 0, stream>>>(out_w, out_w_bf, 1474560);
        rmsnorm_kernel<<<NTOK, 256, 0, stream>>>(x, norm_w, Tbuf);
        gemm_kernel<128, false, false, true><<<dim3(40, 16), 256, 0, stream>>>(
            Tbuf, qkv_w_bf, qkv_b, nullptr, qkvbuf, NTOK, QKV_DIM, HIDDEN);
        rope_apply_kernel<<<2304, 256, 0, stream>>>(qkvbuf);
        attn_mfma_kernel<<<dim3(16, 16, 2), 256, 0, stream>>>(qkvbuf, sinks, attnbuf);
        gemm_kernel<96, true, true, true><<<dim3(30, 16), 256, 0, stream>>>(
            attnbuf, out_w_bf, out_b, x, outp, NTOK, HIDDEN, ATTN_DIM);
    } else {
        // fallback: fp32 B loads (register staging), Tbuf in d_out
        ushort_t* qkvbuf = (ushort_t*)ws;
        ushort_t* attnbuf = (ushort_t*)(ws + 20971520);
        ushort_t* Tbuf = (ushort_t*)d_out;

        rmsnorm_kernel<<<NTOK, 256, 0, stream>>>(x, norm_w, Tbuf);
        gemm_kernel<128, false, false, false><<<dim3(40, 16), 256, 0, stream>>>(
            Tbuf, qkv_w, qkv_b, nullptr, qkvbuf, NTOK, QKV_DIM, HIDDEN);
        rope_apply_kernel<<<2304, 256, 0, stream>>>(qkvbuf);
        attn_mfma_kernel<<<dim3(16, 16, 2), 256, 0, stream>>>(qkvbuf, sinks, attnbuf);
        gemm_kernel<96, true, true, false><<<dim3(30, 16), 256, 0, stream>>>(
            attnbuf, out_w, out_b, x, outp, NTOK, HIDDEN, ATTN_DIM);
    }
}